// Round 2
// baseline (110661.011 us; speedup 1.0000x reference)
//
#include <hip/hip_runtime.h>
#include <math.h>

#define TM1 2047
#define NB 32
#define NV 21
#define HH 336
#define G3 1008
#define CH 256

__device__ __forceinline__ float elu_f(float x){ return x > 0.f ? x : (expf(x) - 1.f); }
__device__ __forceinline__ float sigm_f(float x){ return 1.f / (1.f + expf(-x)); }

// ---------------- quaternion -> euler (zyx) + time-normalize ----------------
// out: x_ws[b][63][TM1]  (channel = 3*v + c), normalized over t per (b, v, c)
__global__ __launch_bounds__(256) void k_euler(const float* __restrict__ xd, float* __restrict__ xout){
  int b = blockIdx.x / NV, v = blockIdx.x % NV;
  const float* q = xd + ((size_t)b * 84 + 4 * v) * TM1;
  float ex[8], ey[8], ez[8];
  float sx = 0.f, sy = 0.f, sz = 0.f;
#pragma unroll
  for(int it = 0; it < 8; ++it){
    int t = threadIdx.x + it * 256;
    float e0 = 0.f, e1 = 0.f, e2 = 0.f;
    if(t < TM1){
      float q0 = q[t], q1 = q[TM1 + t], q2 = q[2 * TM1 + t], q3 = q[3 * TM1 + t];
      e0 = atan2f(2.f * (q0 * q1 - q2 * q3), 1.f - 2.f * (q1 * q1 + q2 * q2));
      float s = 2.f * (q1 * q3 + q0 * q2);
      s = fminf(1.f, fmaxf(-1.f, s));
      e1 = asinf(s);
      e2 = atan2f(2.f * (q0 * q3 - q1 * q2), 1.f - 2.f * (q2 * q2 + q3 * q3));
    }
    ex[it] = e0; ey[it] = e1; ez[it] = e2;
    sx += e0 * e0; sy += e1 * e1; sz += e2 * e2;
  }
  __shared__ float rb[3][256];
  rb[0][threadIdx.x] = sx; rb[1][threadIdx.x] = sy; rb[2][threadIdx.x] = sz;
  __syncthreads();
  if(threadIdx.x < 3){
    float s = 0.f;
    for(int i = 0; i < 256; ++i) s += rb[threadIdx.x][i];
    rb[threadIdx.x][0] = 1.f / fmaxf(sqrtf(s), 1e-12f);
  }
  __syncthreads();
  float i0 = rb[0][0], i1 = rb[1][0], i2 = rb[2][0];
  float* xo = xout + ((size_t)b * 63 + 3 * v) * TM1;
#pragma unroll
  for(int it = 0; it < 8; ++it){
    int t = threadIdx.x + it * 256;
    if(t < TM1){
      xo[t]            = ex[it] * i0;
      xo[TM1 + t]      = ey[it] * i1;
      xo[2 * TM1 + t]  = ez[it] * i2;
    }
  }
}

// ---------------- input projection GEMM (chunked): gx[b][trel][1008] ----------------
// XKT = true : xin layout [b][K][TM1] (full time axis);  false: [b][xrows][K] chunk rows
template<int K, int KC, bool XKT>
__global__ __launch_bounds__(256) void k_gx(const float* __restrict__ xin, int xrows, int xbase,
                                            const float* __restrict__ Wih, const float* __restrict__ bih,
                                            float* __restrict__ gx, int gxrows, int tbase){
  __shared__ float ys[112][68];
  __shared__ float wsm[112][68];
  int trel0 = blockIdx.x * 64;
  int g0 = blockIdx.y * 64;
  int b  = blockIdx.z;
  int gi = threadIdx.x & 15, ti = threadIdx.x >> 4;
  float acc[4][4];
#pragma unroll
  for(int a = 0; a < 4; ++a)
#pragma unroll
    for(int c = 0; c < 4; ++c) acc[a][c] = 0.f;

  for(int k0 = 0; k0 < K; k0 += KC){
    if(XKT){
      for(int idx = threadIdx.x; idx < KC * 64; idx += 256){
        int kk = idx >> 6, tt = idx & 63; int t = tbase + trel0 + tt;
        ys[kk][tt] = (t < TM1) ? xin[((size_t)b * K + k0 + kk) * TM1 + t] : 0.f;
      }
    } else {
      for(int idx = threadIdx.x; idx < 64 * KC; idx += 256){
        int tt = idx / KC, kk = idx % KC; int t = tbase + trel0 + tt;
        ys[kk][tt] = (t < TM1) ? xin[((size_t)b * xrows + (t - xbase)) * K + k0 + kk] : 0.f;
      }
    }
    for(int idx = threadIdx.x; idx < 64 * KC; idx += 256){
      int gg = idx / KC, kk = idx % KC; int g = g0 + gg;
      wsm[kk][gg] = (g < G3) ? Wih[(size_t)g * K + k0 + kk] : 0.f;
    }
    __syncthreads();
    int klim = (K - k0 < KC) ? (K - k0) : KC;
    for(int kk = 0; kk < klim; ++kk){
      float4 xv = *(const float4*)&ys[kk][ti * 4];
      float4 wv = *(const float4*)&wsm[kk][gi * 4];
      float xa[4] = {xv.x, xv.y, xv.z, xv.w};
      float wa[4] = {wv.x, wv.y, wv.z, wv.w};
#pragma unroll
      for(int a = 0; a < 4; ++a)
#pragma unroll
        for(int c = 0; c < 4; ++c) acc[a][c] += xa[a] * wa[c];
    }
    __syncthreads();
  }
#pragma unroll
  for(int a = 0; a < 4; ++a){
    int trel = trel0 + ti * 4 + a;
    int t = tbase + trel;
    if(t >= TM1) continue;
    int g = g0 + gi * 4;
    float* gp = gx + ((size_t)b * gxrows + trel) * G3;
    if(g + 3 < G3){
      float4 o;
      o.x = acc[a][0] + bih[g];   o.y = acc[a][1] + bih[g+1];
      o.z = acc[a][2] + bih[g+2]; o.w = acc[a][3] + bih[g+3];
      *(float4*)&gp[g] = o;
    } else {
#pragma unroll
      for(int c = 0; c < 4; ++c){ if(g + c < G3) gp[g + c] = acc[a][c] + bih[g + c]; }
    }
  }
}

// ---------------- persistent GRU scan (one layer, one time-chunk) ----------------
// 224 WGs = 14 unit-slices (24 units each) x 16 batch-pairs. Whh slice in VGPRs.
// Sync: monotonic per-pair counter (absolute-t target), agent-scope acquire/release.
#define GU 14
#define UU 24
#define SCAN_T 320

__global__ __launch_bounds__(SCAN_T) void k_scan(const float* __restrict__ Whh, const float* __restrict__ bhh,
    const float* __restrict__ gx, int gxrows,
    float* hb0, float* hb1,
    float* __restrict__ yout, int yrows, int ybase,
    float* __restrict__ hT, int* cnt, int t0, int tn){
  int ug = blockIdx.x / 16, pr = blockIdx.x % 16;
  int u0 = ug * UU, b0 = pr * 2;
  int tid = threadIdx.x;
  __shared__ float hl[2][HH];
  __shared__ float part[72][4][2];

  int r = tid >> 2, kq = tid & 3;
  bool act = (tid < 288);               // 72 rows x 4 k-slices
  float w[84];
  if(act){
    int rglob = (r / UU) * HH + u0 + (r % UU);   // gate-major rows: [r | z | n]
    const float* wp = Whh + (size_t)rglob * HH + kq * 84;
#pragma unroll
    for(int j = 0; j < 84; ++j) w[j] = wp[j];
  }
  bool comb = (tid < 48);               // 24 units x 2 batch
  int cu = tid % UU, cb = tid / UU;
  float bh_r = 0.f, bh_z = 0.f, bh_n = 0.f;
  const float* gxp = gx;
  if(comb){
    bh_r = bhh[u0 + cu]; bh_z = bhh[HH + u0 + cu]; bh_n = bhh[2 * HH + u0 + cu];
    gxp = gx + ((size_t)(b0 + cb) * gxrows) * G3 + u0 + cu;
  }
  float* hcur = ((t0 & 1) == 0) ? hb0 : hb1;
  float* hnxt = ((t0 & 1) == 0) ? hb1 : hb0;
  for(int ti = 0; ti < tn; ++ti){
    int t = t0 + ti;
    float gr = 0.f, gz = 0.f, gn = 0.f;
    if(comb){                            // prefetch gx for this step (immutable data)
      const float* gp = gxp + (size_t)ti * G3;
      gr = gp[0]; gz = gp[HH]; gn = gp[2 * HH];
    }
    if(tid == 0 && t > 0){
      int target = GU * t;
      while(__hip_atomic_load(cnt + pr, __ATOMIC_ACQUIRE, __HIP_MEMORY_SCOPE_AGENT) < target)
        __builtin_amdgcn_s_sleep(2);
    }
    __syncthreads();
    for(int idx = tid; idx < 2 * HH; idx += SCAN_T){
      int bs = (idx >= HH), k = idx - bs * HH;
      hl[bs][k] = hcur[(size_t)(b0 + bs) * HH + k];
    }
    __syncthreads();
    if(act){
      float a0 = 0.f, a1 = 0.f;
#pragma unroll
      for(int jj = 0; jj < 21; ++jj){
        float4 h0 = *(const float4*)&hl[0][kq * 84 + jj * 4];
        float4 h1 = *(const float4*)&hl[1][kq * 84 + jj * 4];
        a0 += w[jj*4+0]*h0.x + w[jj*4+1]*h0.y + w[jj*4+2]*h0.z + w[jj*4+3]*h0.w;
        a1 += w[jj*4+0]*h1.x + w[jj*4+1]*h1.y + w[jj*4+2]*h1.z + w[jj*4+3]*h1.w;
      }
      part[r][kq][0] = a0; part[r][kq][1] = a1;
    }
    __syncthreads();
    if(comb){
      float ghr = part[cu][0][cb] + part[cu][1][cb] + part[cu][2][cb] + part[cu][3][cb] + bh_r;
      float ghz = part[24+cu][0][cb] + part[24+cu][1][cb] + part[24+cu][2][cb] + part[24+cu][3][cb] + bh_z;
      float ghn = part[48+cu][0][cb] + part[48+cu][1][cb] + part[48+cu][2][cb] + part[48+cu][3][cb] + bh_n;
      float rg = sigm_f(gr + ghr);
      float zg = sigm_f(gz + ghz);
      float ng = tanhf(gn + rg * ghn);
      float hold = hl[cb][u0 + cu];
      float hnew = (1.f - zg) * ng + zg * hold;
      hnxt[(size_t)(b0 + cb) * HH + u0 + cu] = hnew;
      yout[((size_t)(b0 + cb) * yrows + (t - ybase)) * HH + u0 + cu] = hnew;
      if(t == TM1 - 1) hT[(size_t)(b0 + cb) * HH + u0 + cu] = hnew;
    }
    __threadfence();
    __syncthreads();
    if(tid == 0) __hip_atomic_fetch_add(cnt + pr, 1, __ATOMIC_RELEASE, __HIP_MEMORY_SCOPE_AGENT);
    float* tmp = hcur; hcur = hnxt; hnxt = tmp;
  }
}

// ---------------- fused conv stack + dense head (32-t tile, static LDS 45.6KB) ----------------
__global__ __launch_bounds__(256) void k_head(const float* __restrict__ y1,
   const float* __restrict__ W2, const float* __restrict__ b2,
   const float* __restrict__ W3, const float* __restrict__ b3,
   const float* __restrict__ W3z, const float* __restrict__ b3z,
   const float* __restrict__ Wza, const float* __restrict__ bza,
   const float* __restrict__ W4, const float* __restrict__ b4,
   const float* __restrict__ W5, const float* __restrict__ b5,
   const float* __restrict__ gmm, const float* __restrict__ bet,
   const float* __restrict__ Wc, const float* __restrict__ bc,
   float* __restrict__ out_affs, float* __restrict__ out_lab){
  __shared__ float sm[11402];
  float* aggp = sm;             // [5*32][38]  6080
  float* zinp = sm + 6080;      // [64][36]    2304
  float* zzp  = sm + 8384;      // [64][34]    2176 -> ends 10560
  float* ystp = sm + 10560;     // [42][17]    714  -> ends 11274
  float* affp = sm + 11274;     // [4][32]     128  -> ends 11402
  float* lblA = sm + 6080;      // [128][32]   4096 (aliases zin+zz, dead by then)
  float* lgpp = sm;             // [32][8][4]  1024 (aliases aggp, dead by then)
  int t0 = blockIdx.x * 32;
  int b  = blockIdx.y;
  int tid = threadIdx.x;

  for(int i = tid; i < 6080; i += 256) aggp[i] = 0.f;
  for(int i = tid; i < 2304; i += 256) zinp[i] = 0.f;
  __syncthreads();

  const int   vg_[21] = {0,3,3,3,3,4,4,4,4,0,0,0,0,1,1,1,1,2,2,2,2};
  const float vw_[21] = {0.1f,0.1f,0.2f,0.3f,0.4f,0.1f,0.2f,0.3f,0.4f,
                         0.1f,0.2f,0.2f,0.4f,0.1f,0.2f,0.3f,0.4f,0.1f,0.2f,0.3f,0.4f};

  // --- per-joint conv(k5,p2)+elu, group-weighted accumulate into aggp ---
  {
    int o = tid >> 3, q = tid & 7;                 // o<32, ts = q*5+j
    for(int v = 0; v < NV; ++v){
      for(int idx = tid; idx < 42 * 16; idx += 256){
        int ts = idx >> 4, i = idx & 15; int t = t0 - 5 + ts;
        ystp[ts * 17 + i] = (t >= 0 && t < TM1) ? y1[((size_t)b * TM1 + t) * HH + v * 16 + i] : 0.f;
      }
      __syncthreads();
      int g = vg_[v]; float wv = vw_[v];
      const float* wp = W2 + v * 2560 + o * 80;
      float acc5[5];
      float bias = b2[v * 32 + o];
#pragma unroll
      for(int j = 0; j < 5; ++j) acc5[j] = bias;
#pragma unroll
      for(int i = 0; i < 16; ++i){
        float w0 = wp[i*5+0], w1 = wp[i*5+1], w2v = wp[i*5+2], w3v = wp[i*5+3], w4v = wp[i*5+4];
#pragma unroll
        for(int j = 0; j < 5; ++j){
          int ts = q * 5 + j;
          if(ts < 38){
            acc5[j] += w0*ystp[ts*17+i] + w1*ystp[(ts+1)*17+i] + w2v*ystp[(ts+2)*17+i]
                     + w3v*ystp[(ts+3)*17+i] + w4v*ystp[(ts+4)*17+i];
          }
        }
      }
#pragma unroll
      for(int j = 0; j < 5; ++j){
        int ts = q * 5 + j;
        if(ts < 38){
          int t = t0 - 3 + ts;
          if(t >= 0 && t < TM1) aggp[(g * 32 + o) * 38 + ts] += wv * elu_f(acc5[j]);
        }
      }
      __syncthreads();
    }
  }

  // --- 5x group conv(k3,p1)+elu, weighted sum into zinp ---
  {
    int c = tid >> 2, q = tid & 3;                 // c<64, ts = q*9+j (36)
    for(int k5 = 0; k5 < 5; ++k5){
      float coef = (k5 == 0) ? 0.12f : 0.22f;
      const float* wp = W3 + k5 * 6144 + c * 96;
      float accv[9];
      float bias = b3[k5 * 64 + c];
#pragma unroll
      for(int j = 0; j < 9; ++j) accv[j] = bias;
      for(int i = 0; i < 32; ++i){
        float w0 = wp[i*3+0], w1 = wp[i*3+1], w2v = wp[i*3+2];
        const float* ap = &aggp[(k5 * 32 + i) * 38 + q * 9];
#pragma unroll
        for(int j = 0; j < 9; ++j)
          accv[j] += w0*ap[j] + w1*ap[j+1] + w2v*ap[j+2];
      }
      __syncthreads();   // aggp fully read before any zinp write? zinp separate buffer; sync for uniformity
#pragma unroll
      for(int j = 0; j < 9; ++j){
        int ts = q * 9 + j;
        int t = t0 - 2 + ts;
        if(t >= 0 && t < TM1) zinp[c * 36 + ts] += coef * elu_f(accv[j]);
      }
      __syncthreads();
    }
  }

  // --- conv(k3,p1)+elu -> z (zzp) ---
  {
    int c = tid >> 2, q = tid & 3;                 // ts = q*9+j, guard <34
    const float* wp = W3z + c * 192;
    float accv[9];
    float bias = b3z[c];
#pragma unroll
    for(int j = 0; j < 9; ++j) accv[j] = bias;
    for(int i = 0; i < 64; ++i){
      float w0 = wp[i*3+0], w1 = wp[i*3+1], w2v = wp[i*3+2];
      const float* zp = &zinp[i * 36 + q * 9];
#pragma unroll
      for(int j = 0; j < 9; ++j)
        accv[j] += w0*zp[j] + w1*zp[j+1] + w2v*zp[j+2];
    }
    __syncthreads();
#pragma unroll
    for(int j = 0; j < 9; ++j){
      int ts = q * 9 + j;
      if(ts < 34){
        int t = t0 - 1 + ts;
        zzp[c * 34 + ts] = (t >= 0 && t < TM1) ? elu_f(accv[j]) : 0.f;
      }
    }
    __syncthreads();
  }

  // --- affs conv(k3,p1)+elu (output, transposed) ---
  if(tid < 128){
    int a = tid >> 5, tt = tid & 31;
    const float* wp = Wza + a * 192;
    float acc = bza[a];
    for(int i = 0; i < 64; ++i){
      const float* zp = &zzp[i * 34 + tt];
      acc += wp[i*3+0]*zp[0] + wp[i*3+1]*zp[1] + wp[i*3+2]*zp[2];
    }
    float av = elu_f(acc);
    affp[a * 32 + tt] = av;
    int t = t0 + tt;
    if(t < TM1) out_affs[((size_t)b * TM1 + t) * 4 + a] = av;
  }
  __syncthreads();

  // --- lbl1 = elu(W4 . affs + b4) -> lblA[128][32] (overwrites zin/zz) ---
  for(int idx = tid; idx < 4096; idx += 256){
    int d = idx >> 5, tt = idx & 31;
    float acc = b4[d] + W4[d*4+0]*affp[tt] + W4[d*4+1]*affp[32+tt]
              + W4[d*4+2]*affp[64+tt] + W4[d*4+3]*affp[96+tt];
    lblA[idx] = elu_f(acc);
  }
  __syncthreads();

  // --- lbl2 = elu(W5 . lbl1 + b5); BN over t; logits; sigmoid ---
  {
    int tt = tid >> 3, dg = tid & 7;               // d = dg*16+dd
    float l2[16];
#pragma unroll
    for(int dd = 0; dd < 16; ++dd) l2[dd] = b5[dg * 16 + dd];
    for(int cc = 0; cc < 128; ++cc){
      float xv = lblA[cc * 32 + tt];
#pragma unroll
      for(int dd = 0; dd < 16; ++dd)
        l2[dd] += W5[(dg * 16 + dd) * 128 + cc] * xv;
    }
    int t = t0 + tt;
    float sc = 0.f, bb = 0.f;
    if(t < TM1){ sc = gmm[t] * rsqrtf(1.f + 1e-5f); bb = bet[t]; }
    float lg[4] = {0.f, 0.f, 0.f, 0.f};
#pragma unroll
    for(int dd = 0; dd < 16; ++dd){
      int d = dg * 16 + dd;
      float val = elu_f(l2[dd]) * sc + bb;
#pragma unroll
      for(int c = 0; c < 4; ++c) lg[c] += Wc[c * 128 + d] * val;
    }
    __syncthreads();   // lblA fully consumed before lgpp (aliases aggp, not lblA) write
#pragma unroll
    for(int c = 0; c < 4; ++c) lgpp[(tt * 8 + dg) * 4 + c] = lg[c];
  }
  __syncthreads();
  if(tid < 128){
    int tt = tid >> 2, c = tid & 3;
    float s = bc[c];
#pragma unroll
    for(int dg = 0; dg < 8; ++dg) s += lgpp[(tt * 8 + dg) * 4 + c];
    int ta = t0 + tt;
    if(ta < TM1) out_lab[((size_t)b * TM1 + ta) * 4 + c] = sigm_f(s);
  }
}

extern "C" void kernel_launch(void* const* d_in, const int* in_sizes, int n_in,
                              void* d_out, int out_size, void* d_ws, size_t ws_size,
                              hipStream_t stream){
  (void)in_sizes; (void)n_in; (void)out_size; (void)ws_size;
  const float* x_diffs = (const float*)d_in[1];
  const float* h_init  = (const float*)d_in[3];
  const float* Wih0 = (const float*)d_in[4];
  const float* Whh0 = (const float*)d_in[5];
  const float* bih0 = (const float*)d_in[6];
  const float* bhh0 = (const float*)d_in[7];
  const float* Wih1 = (const float*)d_in[8];
  const float* Whh1 = (const float*)d_in[9];
  const float* bih1 = (const float*)d_in[10];
  const float* bhh1 = (const float*)d_in[11];
  const float* W2  = (const float*)d_in[12];
  const float* b2  = (const float*)d_in[13];
  const float* W3  = (const float*)d_in[14];
  const float* b3  = (const float*)d_in[15];
  const float* W3z = (const float*)d_in[16];
  const float* b3z = (const float*)d_in[17];
  const float* Wza = (const float*)d_in[18];
  const float* bza = (const float*)d_in[19];
  const float* W4  = (const float*)d_in[20];
  const float* b4  = (const float*)d_in[21];
  const float* W5  = (const float*)d_in[22];
  const float* b5  = (const float*)d_in[23];
  const float* gmm = (const float*)d_in[24];
  const float* bet = (const float*)d_in[25];
  const float* Wc  = (const float*)d_in[26];
  const float* bc  = (const float*)d_in[27];
  float* out = (float*)d_out;

  // workspace layout (floats): total ~37.2M (~149 MB)
  float* ws   = (float*)d_ws;
  float* x_ws = ws;                       // 32*63*2047      = 4,126,752
  float* y1   = x_ws + 4126752;           // 32*2047*336     = 22,009,344
  float* gxb  = y1 + 22009344;            // 32*256*1008     =  8,257,536
  float* y0c  = gxb + 8257536;            // 32*256*336      =  2,752,512
  float* hb   = y0c + 2752512;            // 4*32*336        =     43,008
  int*   cnt  = (int*)(hb + 43008);       // 32 ints

  float* out_affs = out;
  float* out_lab  = out + (size_t)NB * TM1 * 4;
  float* hT0 = out + 2 * (size_t)NB * TM1 * 4;
  float* hT1 = hT0 + NB * HH;

  hipMemsetAsync(cnt, 0, 32 * sizeof(int), stream);
  hipMemcpyAsync(hb,               h_init,           NB * HH * sizeof(float), hipMemcpyDeviceToDevice, stream);
  hipMemcpyAsync(hb + 2 * NB * HH, h_init + NB * HH, NB * HH * sizeof(float), hipMemcpyDeviceToDevice, stream);

  k_euler<<<dim3(NB * NV), 256, 0, stream>>>(x_diffs, x_ws);

  for(int c = 0; c < 8; ++c){
    int t0 = c * CH;
    int tn = (TM1 - t0 < CH) ? (TM1 - t0) : CH;
    int gtiles = (tn + 63) / 64;
    k_gx<63, 63, true><<<dim3(gtiles, 16, NB), 256, 0, stream>>>(
        x_ws, 0, 0, Wih0, bih0, gxb, CH, t0);
    k_scan<<<dim3(224), SCAN_T, 0, stream>>>(
        Whh0, bhh0, gxb, CH, hb, hb + NB * HH, y0c, CH, t0, hT0, cnt, t0, tn);
    k_gx<336, 112, false><<<dim3(gtiles, 16, NB), 256, 0, stream>>>(
        y0c, CH, t0, Wih1, bih1, gxb, CH, t0);
    k_scan<<<dim3(224), SCAN_T, 0, stream>>>(
        Whh1, bhh1, gxb, CH, hb + 2 * NB * HH, hb + 3 * NB * HH, y1, TM1, 0, hT1, cnt + 16, t0, tn);
  }

  k_head<<<dim3(64, NB), 256, 0, stream>>>(y1, W2, b2, W3, b3, W3z, b3z, Wza, bza,
                                           W4, b4, W5, b5, gmm, bet, Wc, bc,
                                           out_affs, out_lab);
}

// Round 5
// 28170.197 us; speedup vs baseline: 3.9283x; 3.9283x over previous
//
#include <hip/hip_runtime.h>
#include <math.h>

#define TM1 2047
#define NB 32
#define NV 21
#define HH 336
#define G3 1008
#define CH 256
#define CNT_PAD 64   // ints per counter slot (256B) to kill false sharing

__device__ __forceinline__ float elu_f(float x){ return x > 0.f ? x : (expf(x) - 1.f); }
__device__ __forceinline__ float sigm_f(float x){ return 1.f / (1.f + expf(-x)); }

// ---------------- quaternion -> euler (zyx) + time-normalize ----------------
__global__ __launch_bounds__(256) void k_euler(const float* __restrict__ xd, float* __restrict__ xout){
  int b = blockIdx.x / NV, v = blockIdx.x % NV;
  const float* q = xd + ((size_t)b * 84 + 4 * v) * TM1;
  float ex[8], ey[8], ez[8];
  float sx = 0.f, sy = 0.f, sz = 0.f;
#pragma unroll
  for(int it = 0; it < 8; ++it){
    int t = threadIdx.x + it * 256;
    float e0 = 0.f, e1 = 0.f, e2 = 0.f;
    if(t < TM1){
      float q0 = q[t], q1 = q[TM1 + t], q2 = q[2 * TM1 + t], q3 = q[3 * TM1 + t];
      e0 = atan2f(2.f * (q0 * q1 - q2 * q3), 1.f - 2.f * (q1 * q1 + q2 * q2));
      float s = 2.f * (q1 * q3 + q0 * q2);
      s = fminf(1.f, fmaxf(-1.f, s));
      e1 = asinf(s);
      e2 = atan2f(2.f * (q0 * q3 - q1 * q2), 1.f - 2.f * (q2 * q2 + q3 * q3));
    }
    ex[it] = e0; ey[it] = e1; ez[it] = e2;
    sx += e0 * e0; sy += e1 * e1; sz += e2 * e2;
  }
  __shared__ float rb[3][256];
  rb[0][threadIdx.x] = sx; rb[1][threadIdx.x] = sy; rb[2][threadIdx.x] = sz;
  __syncthreads();
  if(threadIdx.x < 3){
    float s = 0.f;
    for(int i = 0; i < 256; ++i) s += rb[threadIdx.x][i];
    rb[threadIdx.x][0] = 1.f / fmaxf(sqrtf(s), 1e-12f);
  }
  __syncthreads();
  float i0 = rb[0][0], i1 = rb[1][0], i2 = rb[2][0];
  float* xo = xout + ((size_t)b * 63 + 3 * v) * TM1;
#pragma unroll
  for(int it = 0; it < 8; ++it){
    int t = threadIdx.x + it * 256;
    if(t < TM1){
      xo[t]            = ex[it] * i0;
      xo[TM1 + t]      = ey[it] * i1;
      xo[2 * TM1 + t]  = ez[it] * i2;
    }
  }
}

// ---------------- input projection GEMM (chunked): gx[b][trel][1008] ----------------
template<int K, int KC, bool XKT>
__global__ __launch_bounds__(256) void k_gx(const float* __restrict__ xin, int xrows, int xbase,
                                            const float* __restrict__ Wih, const float* __restrict__ bih,
                                            float* __restrict__ gx, int gxrows, int tbase){
  __shared__ float ys[KC][68];
  __shared__ float wsm[KC][68];
  int trel0 = blockIdx.x * 64;
  int g0 = blockIdx.y * 64;
  int b  = blockIdx.z;
  int gi = threadIdx.x & 15, ti = threadIdx.x >> 4;
  float acc[4][4];
#pragma unroll
  for(int a = 0; a < 4; ++a)
#pragma unroll
    for(int c = 0; c < 4; ++c) acc[a][c] = 0.f;

  for(int k0 = 0; k0 < K; k0 += KC){
    if(XKT){
      for(int idx = threadIdx.x; idx < KC * 64; idx += 256){
        int kk = idx >> 6, tt = idx & 63; int t = tbase + trel0 + tt;
        ys[kk][tt] = (t < TM1) ? xin[((size_t)b * K + k0 + kk) * TM1 + t] : 0.f;
      }
    } else {
      for(int idx = threadIdx.x; idx < 64 * KC; idx += 256){
        int tt = idx / KC, kk = idx % KC; int t = tbase + trel0 + tt;
        ys[kk][tt] = (t < TM1) ? xin[((size_t)b * xrows + (t - xbase)) * K + k0 + kk] : 0.f;
      }
    }
    for(int idx = threadIdx.x; idx < 64 * KC; idx += 256){
      int gg = idx / KC, kk = idx % KC; int g = g0 + gg;
      wsm[kk][gg] = (g < G3) ? Wih[(size_t)g * K + k0 + kk] : 0.f;
    }
    __syncthreads();
    int klim = (K - k0 < KC) ? (K - k0) : KC;
    for(int kk = 0; kk < klim; ++kk){
      float4 xv = *(const float4*)&ys[kk][ti * 4];
      float4 wv = *(const float4*)&wsm[kk][gi * 4];
      float xa[4] = {xv.x, xv.y, xv.z, xv.w};
      float wa[4] = {wv.x, wv.y, wv.z, wv.w};
#pragma unroll
      for(int a = 0; a < 4; ++a)
#pragma unroll
        for(int c = 0; c < 4; ++c) acc[a][c] += xa[a] * wa[c];
    }
    __syncthreads();
  }
#pragma unroll
  for(int a = 0; a < 4; ++a){
    int trel = trel0 + ti * 4 + a;
    int t = tbase + trel;
    if(t >= TM1) continue;
    int g = g0 + gi * 4;
    float* gp = gx + ((size_t)b * gxrows + trel) * G3;
    if(g + 3 < G3){
      float4 o;
      o.x = acc[a][0] + bih[g];   o.y = acc[a][1] + bih[g+1];
      o.z = acc[a][2] + bih[g+2]; o.w = acc[a][3] + bih[g+3];
      *(float4*)&gp[g] = o;
    } else {
#pragma unroll
      for(int c = 0; c < 4; ++c){ if(g + c < G3) gp[g + c] = acc[a][c] + bih[g + c]; }
    }
  }
}

// ---------------- persistent GRU scan (one layer, one time-chunk) ----------------
// 224 WGs = 14 unit-slices (24 units each) x 16 batch-pairs. Whh slice in VGPRs.
// Sync: padded per-pair monotonic counter; RELAXED spin (atomic loads are
// LLC-coherent at agent scope, no per-poll invalidate) + ONE acquire load after
// the spin to order subsequent h reads. Release folded into the fetch_add.
// yout store moved off the critical path (drains during next step's spin).
#define GU 14
#define UU 24
#define SCAN_T 320

__global__ __launch_bounds__(SCAN_T) void k_scan(const float* __restrict__ Whh, const float* __restrict__ bhh,
    const float* __restrict__ gx, int gxrows,
    float* hb0, float* hb1,
    float* __restrict__ yout, int yrows, int ybase,
    float* __restrict__ hT, int* cnt_base, int t0, int tn){
  int ug = blockIdx.x / 16, pr = blockIdx.x % 16;
  int u0 = ug * UU, b0 = pr * 2;
  int tid = threadIdx.x;
  int* cnt = cnt_base + pr * CNT_PAD;
  __shared__ float hl[2][HH];
  __shared__ float part[72][4][2];

  int r = tid >> 2, kq = tid & 3;
  bool act = (tid < 288);               // 72 rows x 4 k-slices
  float w[84];
  if(act){
    int rglob = (r / UU) * HH + u0 + (r % UU);   // gate-major rows: [r | z | n]
    const float* wp = Whh + (size_t)rglob * HH + kq * 84;
#pragma unroll
    for(int j = 0; j < 84; ++j) w[j] = wp[j];
  }
  bool comb = (tid < 48);               // 24 units x 2 batch
  int cu = tid % UU, cb = tid / UU;
  float bh_r = 0.f, bh_z = 0.f, bh_n = 0.f;
  const float* gxp = gx;
  if(comb){
    bh_r = bhh[u0 + cu]; bh_z = bhh[HH + u0 + cu]; bh_n = bhh[2 * HH + u0 + cu];
    gxp = gx + ((size_t)(b0 + cb) * gxrows) * G3 + u0 + cu;
  }
  float* hcur = ((t0 & 1) == 0) ? hb0 : hb1;
  float* hnxt = ((t0 & 1) == 0) ? hb1 : hb0;
  for(int ti = 0; ti < tn; ++ti){
    int t = t0 + ti;
    float gr = 0.f, gz = 0.f, gn = 0.f;
    if(comb){                            // prefetch gx (immutable) — overlaps the spin
      const float* gp = gxp + (size_t)ti * G3;
      gr = gp[0]; gz = gp[HH]; gn = gp[2 * HH];
    }
    if(tid == 0 && t > 0){
      int target = GU * t;
      while(__hip_atomic_load(cnt, __ATOMIC_RELAXED, __HIP_MEMORY_SCOPE_AGENT) < target)
        __builtin_amdgcn_s_sleep(1);
      // one acquire load to order subsequent hcur reads (single invalidate/step)
      __hip_atomic_load(cnt, __ATOMIC_ACQUIRE, __HIP_MEMORY_SCOPE_AGENT);
    }
    __syncthreads();
    for(int idx = tid; idx < 2 * HH; idx += SCAN_T){
      int bs = (idx >= HH), k = idx - bs * HH;
      hl[bs][k] = hcur[(size_t)(b0 + bs) * HH + k];
    }
    __syncthreads();
    if(act){
      float a0 = 0.f, a1 = 0.f;
#pragma unroll
      for(int jj = 0; jj < 21; ++jj){
        float4 h0 = *(const float4*)&hl[0][kq * 84 + jj * 4];
        float4 h1 = *(const float4*)&hl[1][kq * 84 + jj * 4];
        a0 += w[jj*4+0]*h0.x + w[jj*4+1]*h0.y + w[jj*4+2]*h0.z + w[jj*4+3]*h0.w;
        a1 += w[jj*4+0]*h1.x + w[jj*4+1]*h1.y + w[jj*4+2]*h1.z + w[jj*4+3]*h1.w;
      }
      part[r][kq][0] = a0; part[r][kq][1] = a1;
    }
    __syncthreads();
    float hnew = 0.f;
    if(comb){
      float ghr = part[cu][0][cb] + part[cu][1][cb] + part[cu][2][cb] + part[cu][3][cb] + bh_r;
      float ghz = part[24+cu][0][cb] + part[24+cu][1][cb] + part[24+cu][2][cb] + part[24+cu][3][cb] + bh_z;
      float ghn = part[48+cu][0][cb] + part[48+cu][1][cb] + part[48+cu][2][cb] + part[48+cu][3][cb] + bh_n;
      float rg = sigm_f(gr + ghr);
      float zg = sigm_f(gz + ghz);
      float ng = tanhf(gn + rg * ghn);
      float hold = hl[cb][u0 + cu];
      hnew = (1.f - zg) * ng + zg * hold;
      hnxt[(size_t)(b0 + cb) * HH + u0 + cu] = hnew;
    }
    __syncthreads();                     // drains hnxt stores for all lanes
    if(tid == 0)
      __hip_atomic_fetch_add(cnt, 1, __ATOMIC_RELEASE, __HIP_MEMORY_SCOPE_AGENT);
    if(comb){                            // off critical path: drains during next spin
      yout[((size_t)(b0 + cb) * yrows + (t - ybase)) * HH + u0 + cu] = hnew;
      if(t == TM1 - 1) hT[(size_t)(b0 + cb) * HH + u0 + cu] = hnew;
    }
    float* tmp = hcur; hcur = hnxt; hnxt = tmp;
  }
}

// ---------------- fused conv stack + dense head (32-t tile, static LDS 45.6KB) ----------------
__global__ __launch_bounds__(256) void k_head(const float* __restrict__ y1,
   const float* __restrict__ W2, const float* __restrict__ b2,
   const float* __restrict__ W3, const float* __restrict__ b3,
   const float* __restrict__ W3z, const float* __restrict__ b3z,
   const float* __restrict__ Wza, const float* __restrict__ bza,
   const float* __restrict__ W4, const float* __restrict__ b4,
   const float* __restrict__ W5, const float* __restrict__ b5,
   const float* __restrict__ gmm, const float* __restrict__ bet,
   const float* __restrict__ Wc, const float* __restrict__ bc,
   float* __restrict__ out_affs, float* __restrict__ out_lab){
  __shared__ float sm[11402];
  float* aggp = sm;             // [5*32][38]  6080
  float* zinp = sm + 6080;      // [64][36]    2304
  float* zzp  = sm + 8384;      // [64][34]    2176 -> ends 10560
  float* ystp = sm + 10560;     // [42][17]    714  -> ends 11274
  float* affp = sm + 11274;     // [4][32]     128  -> ends 11402
  float* lblA = sm + 6080;      // [128][32]   4096 (aliases zin+zz, dead by then)
  float* lgpp = sm;             // [32][8][4]  1024 (aliases aggp, dead by then)
  int t0 = blockIdx.x * 32;
  int b  = blockIdx.y;
  int tid = threadIdx.x;

  for(int i = tid; i < 6080; i += 256) aggp[i] = 0.f;
  for(int i = tid; i < 2304; i += 256) zinp[i] = 0.f;
  __syncthreads();

  const int   vg_[21] = {0,3,3,3,3,4,4,4,4,0,0,0,0,1,1,1,1,2,2,2,2};
  const float vw_[21] = {0.1f,0.1f,0.2f,0.3f,0.4f,0.1f,0.2f,0.3f,0.4f,
                         0.1f,0.2f,0.2f,0.4f,0.1f,0.2f,0.3f,0.4f,0.1f,0.2f,0.3f,0.4f};

  // --- per-joint conv(k5,p2)+elu, group-weighted accumulate into aggp ---
  {
    int o = tid >> 3, q = tid & 7;                 // o<32, ts = q*5+j
    for(int v = 0; v < NV; ++v){
      for(int idx = tid; idx < 42 * 16; idx += 256){
        int ts = idx >> 4, i = idx & 15; int t = t0 - 5 + ts;
        ystp[ts * 17 + i] = (t >= 0 && t < TM1) ? y1[((size_t)b * TM1 + t) * HH + v * 16 + i] : 0.f;
      }
      __syncthreads();
      int g = vg_[v]; float wv = vw_[v];
      const float* wp = W2 + v * 2560 + o * 80;
      float acc5[5];
      float bias = b2[v * 32 + o];
#pragma unroll
      for(int j = 0; j < 5; ++j) acc5[j] = bias;
#pragma unroll
      for(int i = 0; i < 16; ++i){
        float w0 = wp[i*5+0], w1 = wp[i*5+1], w2v = wp[i*5+2], w3v = wp[i*5+3], w4v = wp[i*5+4];
#pragma unroll
        for(int j = 0; j < 5; ++j){
          int ts = q * 5 + j;
          if(ts < 38){
            acc5[j] += w0*ystp[ts*17+i] + w1*ystp[(ts+1)*17+i] + w2v*ystp[(ts+2)*17+i]
                     + w3v*ystp[(ts+3)*17+i] + w4v*ystp[(ts+4)*17+i];
          }
        }
      }
#pragma unroll
      for(int j = 0; j < 5; ++j){
        int ts = q * 5 + j;
        if(ts < 38){
          int t = t0 - 3 + ts;
          if(t >= 0 && t < TM1) aggp[(g * 32 + o) * 38 + ts] += wv * elu_f(acc5[j]);
        }
      }
      __syncthreads();
    }
  }

  // --- 5x group conv(k3,p1)+elu, weighted sum into zinp ---
  {
    int c = tid >> 2, q = tid & 3;                 // c<64, ts = q*9+j (36)
    for(int k5 = 0; k5 < 5; ++k5){
      float coef = (k5 == 0) ? 0.12f : 0.22f;
      const float* wp = W3 + k5 * 6144 + c * 96;
      float accv[9];
      float bias = b3[k5 * 64 + c];
#pragma unroll
      for(int j = 0; j < 9; ++j) accv[j] = bias;
      for(int i = 0; i < 32; ++i){
        float w0 = wp[i*3+0], w1 = wp[i*3+1], w2v = wp[i*3+2];
        const float* ap = &aggp[(k5 * 32 + i) * 38 + q * 9];
#pragma unroll
        for(int j = 0; j < 9; ++j)
          accv[j] += w0*ap[j] + w1*ap[j+1] + w2v*ap[j+2];
      }
      __syncthreads();
#pragma unroll
      for(int j = 0; j < 9; ++j){
        int ts = q * 9 + j;
        int t = t0 - 2 + ts;
        if(t >= 0 && t < TM1) zinp[c * 36 + ts] += coef * elu_f(accv[j]);
      }
      __syncthreads();
    }
  }

  // --- conv(k3,p1)+elu -> z (zzp) ---
  {
    int c = tid >> 2, q = tid & 3;                 // ts = q*9+j, guard <34
    const float* wp = W3z + c * 192;
    float accv[9];
    float bias = b3z[c];
#pragma unroll
    for(int j = 0; j < 9; ++j) accv[j] = bias;
    for(int i = 0; i < 64; ++i){
      float w0 = wp[i*3+0], w1 = wp[i*3+1], w2v = wp[i*3+2];
      const float* zp = &zinp[i * 36 + q * 9];
#pragma unroll
      for(int j = 0; j < 9; ++j)
        accv[j] += w0*zp[j] + w1*zp[j+1] + w2v*zp[j+2];
    }
    __syncthreads();
#pragma unroll
    for(int j = 0; j < 9; ++j){
      int ts = q * 9 + j;
      if(ts < 34){
        int t = t0 - 1 + ts;
        zzp[c * 34 + ts] = (t >= 0 && t < TM1) ? elu_f(accv[j]) : 0.f;
      }
    }
    __syncthreads();
  }

  // --- affs conv(k3,p1)+elu (output, transposed) ---
  if(tid < 128){
    int a = tid >> 5, tt = tid & 31;
    const float* wp = Wza + a * 192;
    float acc = bza[a];
    for(int i = 0; i < 64; ++i){
      const float* zp = &zzp[i * 34 + tt];
      acc += wp[i*3+0]*zp[0] + wp[i*3+1]*zp[1] + wp[i*3+2]*zp[2];
    }
    float av = elu_f(acc);
    affp[a * 32 + tt] = av;
    int t = t0 + tt;
    if(t < TM1) out_affs[((size_t)b * TM1 + t) * 4 + a] = av;
  }
  __syncthreads();

  // --- lbl1 = elu(W4 . affs + b4) -> lblA[128][32] (overwrites zin/zz) ---
  for(int idx = tid; idx < 4096; idx += 256){
    int d = idx >> 5, tt = idx & 31;
    float acc = b4[d] + W4[d*4+0]*affp[tt] + W4[d*4+1]*affp[32+tt]
              + W4[d*4+2]*affp[64+tt] + W4[d*4+3]*affp[96+tt];
    lblA[idx] = elu_f(acc);
  }
  __syncthreads();

  // --- lbl2 = elu(W5 . lbl1 + b5); BN over t; logits; sigmoid ---
  {
    int tt = tid >> 3, dg = tid & 7;               // d = dg*16+dd
    float l2[16];
#pragma unroll
    for(int dd = 0; dd < 16; ++dd) l2[dd] = b5[dg * 16 + dd];
    for(int cc = 0; cc < 128; ++cc){
      float xv = lblA[cc * 32 + tt];
#pragma unroll
      for(int dd = 0; dd < 16; ++dd)
        l2[dd] += W5[(dg * 16 + dd) * 128 + cc] * xv;
    }
    int t = t0 + tt;
    float sc = 0.f, bb = 0.f;
    if(t < TM1){ sc = gmm[t] * rsqrtf(1.f + 1e-5f); bb = bet[t]; }
    float lg[4] = {0.f, 0.f, 0.f, 0.f};
#pragma unroll
    for(int dd = 0; dd < 16; ++dd){
      int d = dg * 16 + dd;
      float val = elu_f(l2[dd]) * sc + bb;
#pragma unroll
      for(int c = 0; c < 4; ++c) lg[c] += Wc[c * 128 + d] * val;
    }
    __syncthreads();
#pragma unroll
    for(int c = 0; c < 4; ++c) lgpp[(tt * 8 + dg) * 4 + c] = lg[c];
  }
  __syncthreads();
  if(tid < 128){
    int tt = tid >> 2, c = tid & 3;
    float s = bc[c];
#pragma unroll
    for(int dg = 0; dg < 8; ++dg) s += lgpp[(tt * 8 + dg) * 4 + c];
    int ta = t0 + tt;
    if(ta < TM1) out_lab[((size_t)b * TM1 + ta) * 4 + c] = sigm_f(s);
  }
}

extern "C" void kernel_launch(void* const* d_in, const int* in_sizes, int n_in,
                              void* d_out, int out_size, void* d_ws, size_t ws_size,
                              hipStream_t stream){
  (void)in_sizes; (void)n_in; (void)out_size; (void)ws_size;
  const float* x_diffs = (const float*)d_in[1];
  const float* h_init  = (const float*)d_in[3];
  const float* Wih0 = (const float*)d_in[4];
  const float* Whh0 = (const float*)d_in[5];
  const float* bih0 = (const float*)d_in[6];
  const float* bhh0 = (const float*)d_in[7];
  const float* Wih1 = (const float*)d_in[8];
  const float* Whh1 = (const float*)d_in[9];
  const float* bih1 = (const float*)d_in[10];
  const float* bhh1 = (const float*)d_in[11];
  const float* W2  = (const float*)d_in[12];
  const float* b2  = (const float*)d_in[13];
  const float* W3  = (const float*)d_in[14];
  const float* b3  = (const float*)d_in[15];
  const float* W3z = (const float*)d_in[16];
  const float* b3z = (const float*)d_in[17];
  const float* Wza = (const float*)d_in[18];
  const float* bza = (const float*)d_in[19];
  const float* W4  = (const float*)d_in[20];
  const float* b4  = (const float*)d_in[21];
  const float* W5  = (const float*)d_in[22];
  const float* b5  = (const float*)d_in[23];
  const float* gmm = (const float*)d_in[24];
  const float* bet = (const float*)d_in[25];
  const float* Wc  = (const float*)d_in[26];
  const float* bc  = (const float*)d_in[27];
  float* out = (float*)d_out;

  // workspace layout (floats): total ~149 MB
  float* ws   = (float*)d_ws;
  float* x_ws = ws;                       // 32*63*2047      = 4,126,752
  float* y1   = x_ws + 4126752;           // 32*2047*336     = 22,009,344
  float* gxb  = y1 + 22009344;            // 32*256*1008     =  8,257,536
  float* y0c  = gxb + 8257536;            // 32*256*336      =  2,752,512
  float* hb   = y0c + 2752512;            // 4*32*336        =     43,008
  int*   cnt  = (int*)(hb + 43008);       // 32 * CNT_PAD ints

  float* out_affs = out;
  float* out_lab  = out + (size_t)NB * TM1 * 4;
  float* hT0 = out + 2 * (size_t)NB * TM1 * 4;
  float* hT1 = hT0 + NB * HH;

  (void)hipMemsetAsync(cnt, 0, 32 * CNT_PAD * sizeof(int), stream);
  (void)hipMemcpyAsync(hb,               h_init,           NB * HH * sizeof(float), hipMemcpyDeviceToDevice, stream);
  (void)hipMemcpyAsync(hb + 2 * NB * HH, h_init + NB * HH, NB * HH * sizeof(float), hipMemcpyDeviceToDevice, stream);

  k_euler<<<dim3(NB * NV), 256, 0, stream>>>(x_diffs, x_ws);

  for(int c = 0; c < 8; ++c){
    int t0 = c * CH;
    int tn = (TM1 - t0 < CH) ? (TM1 - t0) : CH;
    int gtiles = (tn + 63) / 64;
    k_gx<63, 63, true><<<dim3(gtiles, 16, NB), 256, 0, stream>>>(
        x_ws, 0, 0, Wih0, bih0, gxb, CH, t0);
    k_scan<<<dim3(224), SCAN_T, 0, stream>>>(
        Whh0, bhh0, gxb, CH, hb, hb + NB * HH, y0c, CH, t0, hT0, cnt, t0, tn);
    k_gx<336, 112, false><<<dim3(gtiles, 16, NB), 256, 0, stream>>>(
        y0c, CH, t0, Wih1, bih1, gxb, CH, t0);
    k_scan<<<dim3(224), SCAN_T, 0, stream>>>(
        Whh1, bhh1, gxb, CH, hb + 2 * NB * HH, hb + 3 * NB * HH, y1, TM1, 0, hT1, cnt + 16 * CNT_PAD, t0, tn);
  }

  k_head<<<dim3(64, NB), 256, 0, stream>>>(y1, W2, b2, W3, b3, W3z, b3z, Wza, bza,
                                           W4, b4, W5, b5, gmm, bet, Wc, bc,
                                           out_affs, out_lab);
}

// Round 7
// 14719.958 us; speedup vs baseline: 7.5178x; 1.9137x over previous
//
#include <hip/hip_runtime.h>
#include <math.h>

#define TM1 2047
#define NB 32
#define NV 21
#define HH 336
#define G3 1008
#define CH 256
#define FLG_STRIDE 32   // ints per flag slot (128B) to kill false sharing

__device__ __forceinline__ float elu_f(float x){ return x > 0.f ? x : (expf(x) - 1.f); }
__device__ __forceinline__ float sigm_f(float x){ return 1.f / (1.f + expf(-x)); }

// ---------------- quaternion -> euler (zyx) + time-normalize ----------------
__global__ __launch_bounds__(256) void k_euler(const float* __restrict__ xd, float* __restrict__ xout){
  int b = blockIdx.x / NV, v = blockIdx.x % NV;
  const float* q = xd + ((size_t)b * 84 + 4 * v) * TM1;
  float ex[8], ey[8], ez[8];
  float sx = 0.f, sy = 0.f, sz = 0.f;
#pragma unroll
  for(int it = 0; it < 8; ++it){
    int t = threadIdx.x + it * 256;
    float e0 = 0.f, e1 = 0.f, e2 = 0.f;
    if(t < TM1){
      float q0 = q[t], q1 = q[TM1 + t], q2 = q[2 * TM1 + t], q3 = q[3 * TM1 + t];
      e0 = atan2f(2.f * (q0 * q1 - q2 * q3), 1.f - 2.f * (q1 * q1 + q2 * q2));
      float s = 2.f * (q1 * q3 + q0 * q2);
      s = fminf(1.f, fmaxf(-1.f, s));
      e1 = asinf(s);
      e2 = atan2f(2.f * (q0 * q3 - q1 * q2), 1.f - 2.f * (q2 * q2 + q3 * q3));
    }
    ex[it] = e0; ey[it] = e1; ez[it] = e2;
    sx += e0 * e0; sy += e1 * e1; sz += e2 * e2;
  }
  __shared__ float rb[3][256];
  rb[0][threadIdx.x] = sx; rb[1][threadIdx.x] = sy; rb[2][threadIdx.x] = sz;
  __syncthreads();
  if(threadIdx.x < 3){
    float s = 0.f;
    for(int i = 0; i < 256; ++i) s += rb[threadIdx.x][i];
    rb[threadIdx.x][0] = 1.f / fmaxf(sqrtf(s), 1e-12f);
  }
  __syncthreads();
  float i0 = rb[0][0], i1 = rb[1][0], i2 = rb[2][0];
  float* xo = xout + ((size_t)b * 63 + 3 * v) * TM1;
#pragma unroll
  for(int it = 0; it < 8; ++it){
    int t = threadIdx.x + it * 256;
    if(t < TM1){
      xo[t]            = ex[it] * i0;
      xo[TM1 + t]      = ey[it] * i1;
      xo[2 * TM1 + t]  = ez[it] * i2;
    }
  }
}

// ---------------- input projection GEMM (chunked): gx[b][trel][1008] ----------------
template<int K, int KC, bool XKT>
__global__ __launch_bounds__(256) void k_gx(const float* __restrict__ xin, int xrows, int xbase,
                                            const float* __restrict__ Wih, const float* __restrict__ bih,
                                            float* __restrict__ gx, int gxrows, int tbase){
  __shared__ float ys[KC][68];
  __shared__ float wsm[KC][68];
  int trel0 = blockIdx.x * 64;
  int g0 = blockIdx.y * 64;
  int b  = blockIdx.z;
  int gi = threadIdx.x & 15, ti = threadIdx.x >> 4;
  float acc[4][4];
#pragma unroll
  for(int a = 0; a < 4; ++a)
#pragma unroll
    for(int c = 0; c < 4; ++c) acc[a][c] = 0.f;

  for(int k0 = 0; k0 < K; k0 += KC){
    if(XKT){
      for(int idx = threadIdx.x; idx < KC * 64; idx += 256){
        int kk = idx >> 6, tt = idx & 63; int t = tbase + trel0 + tt;
        ys[kk][tt] = (t < TM1) ? xin[((size_t)b * K + k0 + kk) * TM1 + t] : 0.f;
      }
    } else {
      for(int idx = threadIdx.x; idx < 64 * KC; idx += 256){
        int tt = idx / KC, kk = idx % KC; int t = tbase + trel0 + tt;
        ys[kk][tt] = (t < TM1) ? xin[((size_t)b * xrows + (t - xbase)) * K + k0 + kk] : 0.f;
      }
    }
    for(int idx = threadIdx.x; idx < 64 * KC; idx += 256){
      int gg = idx / KC, kk = idx % KC; int g = g0 + gg;
      wsm[kk][gg] = (g < G3) ? Wih[(size_t)g * K + k0 + kk] : 0.f;
    }
    __syncthreads();
    int klim = (K - k0 < KC) ? (K - k0) : KC;
    for(int kk = 0; kk < klim; ++kk){
      float4 xv = *(const float4*)&ys[kk][ti * 4];
      float4 wv = *(const float4*)&wsm[kk][gi * 4];
      float xa[4] = {xv.x, xv.y, xv.z, xv.w};
      float wa[4] = {wv.x, wv.y, wv.z, wv.w};
#pragma unroll
      for(int a = 0; a < 4; ++a)
#pragma unroll
        for(int c = 0; c < 4; ++c) acc[a][c] += xa[a] * wa[c];
    }
    __syncthreads();
  }
#pragma unroll
  for(int a = 0; a < 4; ++a){
    int trel = trel0 + ti * 4 + a;
    int t = tbase + trel;
    if(t >= TM1) continue;
    int g = g0 + gi * 4;
    float* gp = gx + ((size_t)b * gxrows + trel) * G3;
    if(g + 3 < G3){
      float4 o;
      o.x = acc[a][0] + bih[g];   o.y = acc[a][1] + bih[g+1];
      o.z = acc[a][2] + bih[g+2]; o.w = acc[a][3] + bih[g+3];
      *(float4*)&gp[g] = o;
    } else {
#pragma unroll
      for(int c = 0; c < 4; ++c){ if(g + c < G3) gp[g + c] = acc[a][c] + bih[g + c]; }
    }
  }
}

// ---------------- persistent GRU scan (one layer, one time-chunk) ----------------
// 128 WGs = 8 unit-slices (42 units each) x 16 batch-pairs. Whh slice in VGPRs.
// Sync: per-WG flag (128B apart), polled in parallel by lanes 0..7. ALL h-state
// and flags use RELAXED agent-scope atomics (LLC-coherent, cache-bypassing) --
// no acquire invalidates, no release writebacks. Ordering: vmcnt(0) drain at
// __syncthreads before the flag store.
#define GU 8
#define UU 42
#define SCAN_T 512

__global__ __launch_bounds__(SCAN_T) void k_scan(const float* __restrict__ Whh, const float* __restrict__ bhh,
    const float* __restrict__ gx, int gxrows,
    float* hb0, float* hb1,
    float* __restrict__ yout, int yrows, int ybase,
    float* __restrict__ hT, int* flg_base, int t0, int tn){
  int ug = blockIdx.x >> 4, pr = blockIdx.x & 15;
  int u0 = ug * UU, b0 = pr * 2;
  int tid = threadIdx.x;
  int* flg = flg_base + pr * (GU * FLG_STRIDE);
  __shared__ float hl[2][HH];
  __shared__ float part[3 * UU][4][2];

  int r = tid >> 2, kq = tid & 3;
  bool act = (tid < 3 * UU * 4);        // 126 rows x 4 k-slices = 504
  float w[84];
  if(act){
    int rglob = (r / UU) * HH + u0 + (r % UU);   // gate-major rows: [r | z | n]
    const float* wp = Whh + (size_t)rglob * HH + kq * 84;
#pragma unroll
    for(int j = 0; j < 84; ++j) w[j] = wp[j];
  }
  bool comb = (tid < 2 * UU);           // 42 units x 2 batch
  int cu = tid % UU, cb = tid / UU;
  float bh_r = 0.f, bh_z = 0.f, bh_n = 0.f;
  const float* gxp = gx;
  if(comb){
    bh_r = bhh[u0 + cu]; bh_z = bhh[HH + u0 + cu]; bh_n = bhh[2 * HH + u0 + cu];
    gxp = gx + ((size_t)(b0 + cb) * gxrows) * G3 + u0 + cu;
  }
  float* hcur = ((t0 & 1) == 0) ? hb0 : hb1;
  float* hnxt = ((t0 & 1) == 0) ? hb1 : hb0;
  for(int ti = 0; ti < tn; ++ti){
    int t = t0 + ti;
    float gr = 0.f, gz = 0.f, gn = 0.f;
    if(comb){                            // prefetch gx (immutable) — overlaps the spin
      const float* gp = gxp + (size_t)ti * G3;
      gr = gp[0]; gz = gp[HH]; gn = gp[2 * HH];
    }
    if(t > 0 && tid < GU){               // parallel poll: one flag per lane, LLC loads
      while(__hip_atomic_load(flg + tid * FLG_STRIDE, __ATOMIC_RELAXED, __HIP_MEMORY_SCOPE_AGENT) < t)
        __builtin_amdgcn_s_sleep(1);
    }
    __syncthreads();
    for(int idx = tid; idx < 2 * HH; idx += SCAN_T){   // h from LLC (bypass loads)
      int bs = (idx >= HH), k = idx - bs * HH;
      hl[bs][k] = __hip_atomic_load(&hcur[(size_t)(b0 + bs) * HH + k],
                                    __ATOMIC_RELAXED, __HIP_MEMORY_SCOPE_AGENT);
    }
    __syncthreads();
    if(act){
      float a0 = 0.f, a1 = 0.f;
#pragma unroll
      for(int jj = 0; jj < 21; ++jj){
        float4 h0 = *(const float4*)&hl[0][kq * 84 + jj * 4];
        float4 h1 = *(const float4*)&hl[1][kq * 84 + jj * 4];
        a0 += w[jj*4+0]*h0.x + w[jj*4+1]*h0.y + w[jj*4+2]*h0.z + w[jj*4+3]*h0.w;
        a1 += w[jj*4+0]*h1.x + w[jj*4+1]*h1.y + w[jj*4+2]*h1.z + w[jj*4+3]*h1.w;
      }
      part[r][kq][0] = a0; part[r][kq][1] = a1;
    }
    __syncthreads();
    float hnew = 0.f;
    if(comb){
      float ghr = part[cu][0][cb] + part[cu][1][cb] + part[cu][2][cb] + part[cu][3][cb] + bh_r;
      float ghz = part[UU+cu][0][cb] + part[UU+cu][1][cb] + part[UU+cu][2][cb] + part[UU+cu][3][cb] + bh_z;
      float ghn = part[2*UU+cu][0][cb] + part[2*UU+cu][1][cb] + part[2*UU+cu][2][cb] + part[2*UU+cu][3][cb] + bh_n;
      float rg = sigm_f(gr + ghr);
      float zg = sigm_f(gz + ghz);
      float ng = tanhf(gn + rg * ghn);
      float hold = hl[cb][u0 + cu];
      hnew = (1.f - zg) * ng + zg * hold;
      __hip_atomic_store(&hnxt[(size_t)(b0 + cb) * HH + u0 + cu], hnew,
                         __ATOMIC_RELAXED, __HIP_MEMORY_SCOPE_AGENT);
    }
    __syncthreads();                     // vmcnt(0) drain: h stores acked at LLC
    if(tid == 0)
      __hip_atomic_store(flg + ug * FLG_STRIDE, t + 1,
                         __ATOMIC_RELAXED, __HIP_MEMORY_SCOPE_AGENT);
    if(comb){                            // off critical path: drains during next spin
      yout[((size_t)(b0 + cb) * yrows + (t - ybase)) * HH + u0 + cu] = hnew;
      if(t == TM1 - 1) hT[(size_t)(b0 + cb) * HH + u0 + cu] = hnew;
    }
    float* tmp = hcur; hcur = hnxt; hnxt = tmp;
  }
}

// ---------------- fused conv stack + dense head (32-t tile, static LDS 45.6KB) ----------------
__global__ __launch_bounds__(256) void k_head(const float* __restrict__ y1,
   const float* __restrict__ W2, const float* __restrict__ b2,
   const float* __restrict__ W3, const float* __restrict__ b3,
   const float* __restrict__ W3z, const float* __restrict__ b3z,
   const float* __restrict__ Wza, const float* __restrict__ bza,
   const float* __restrict__ W4, const float* __restrict__ b4,
   const float* __restrict__ W5, const float* __restrict__ b5,
   const float* __restrict__ gmm, const float* __restrict__ bet,
   const float* __restrict__ Wc, const float* __restrict__ bc,
   float* __restrict__ out_affs, float* __restrict__ out_lab){
  __shared__ float sm[11402];
  float* aggp = sm;             // [5*32][38]  6080
  float* zinp = sm + 6080;      // [64][36]    2304
  float* zzp  = sm + 8384;      // [64][34]    2176 -> ends 10560
  float* ystp = sm + 10560;     // [42][17]    714  -> ends 11274
  float* affp = sm + 11274;     // [4][32]     128  -> ends 11402
  float* lblA = sm + 6080;      // [128][32]   4096 (aliases zin+zz, dead by then)
  float* lgpp = sm;             // [32][8][4]  1024 (aliases aggp, dead by then)
  int t0 = blockIdx.x * 32;
  int b  = blockIdx.y;
  int tid = threadIdx.x;

  for(int i = tid; i < 6080; i += 256) aggp[i] = 0.f;
  for(int i = tid; i < 2304; i += 256) zinp[i] = 0.f;
  __syncthreads();

  const int   vg_[21] = {0,3,3,3,3,4,4,4,4,0,0,0,0,1,1,1,1,2,2,2,2};
  const float vw_[21] = {0.1f,0.1f,0.2f,0.3f,0.4f,0.1f,0.2f,0.3f,0.4f,
                         0.1f,0.2f,0.2f,0.4f,0.1f,0.2f,0.3f,0.4f,0.1f,0.2f,0.3f,0.4f};

  // --- per-joint conv(k5,p2)+elu, group-weighted accumulate into aggp ---
  {
    int o = tid >> 3, q = tid & 7;                 // o<32, ts = q*5+j
    for(int v = 0; v < NV; ++v){
      for(int idx = tid; idx < 42 * 16; idx += 256){
        int ts = idx >> 4, i = idx & 15; int t = t0 - 5 + ts;
        ystp[ts * 17 + i] = (t >= 0 && t < TM1) ? y1[((size_t)b * TM1 + t) * HH + v * 16 + i] : 0.f;
      }
      __syncthreads();
      int g = vg_[v]; float wv = vw_[v];
      const float* wp = W2 + v * 2560 + o * 80;
      float acc5[5];
      float bias = b2[v * 32 + o];
#pragma unroll
      for(int j = 0; j < 5; ++j) acc5[j] = bias;
#pragma unroll
      for(int i = 0; i < 16; ++i){
        float w0 = wp[i*5+0], w1 = wp[i*5+1], w2v = wp[i*5+2], w3v = wp[i*5+3], w4v = wp[i*5+4];
#pragma unroll
        for(int j = 0; j < 5; ++j){
          int ts = q * 5 + j;
          if(ts < 38){
            acc5[j] += w0*ystp[ts*17+i] + w1*ystp[(ts+1)*17+i] + w2v*ystp[(ts+2)*17+i]
                     + w3v*ystp[(ts+3)*17+i] + w4v*ystp[(ts+4)*17+i];
          }
        }
      }
#pragma unroll
      for(int j = 0; j < 5; ++j){
        int ts = q * 5 + j;
        if(ts < 38){
          int t = t0 - 3 + ts;
          if(t >= 0 && t < TM1) aggp[(g * 32 + o) * 38 + ts] += wv * elu_f(acc5[j]);
        }
      }
      __syncthreads();
    }
  }

  // --- 5x group conv(k3,p1)+elu, weighted sum into zinp ---
  {
    int c = tid >> 2, q = tid & 3;                 // c<64, ts = q*9+j (36)
    for(int k5 = 0; k5 < 5; ++k5){
      float coef = (k5 == 0) ? 0.12f : 0.22f;
      const float* wp = W3 + k5 * 6144 + c * 96;
      float accv[9];
      float bias = b3[k5 * 64 + c];
#pragma unroll
      for(int j = 0; j < 9; ++j) accv[j] = bias;
      for(int i = 0; i < 32; ++i){
        float w0 = wp[i*3+0], w1 = wp[i*3+1], w2v = wp[i*3+2];
        const float* ap = &aggp[(k5 * 32 + i) * 38 + q * 9];
#pragma unroll
        for(int j = 0; j < 9; ++j)
          accv[j] += w0*ap[j] + w1*ap[j+1] + w2v*ap[j+2];
      }
      __syncthreads();
#pragma unroll
      for(int j = 0; j < 9; ++j){
        int ts = q * 9 + j;
        int t = t0 - 2 + ts;
        if(t >= 0 && t < TM1) zinp[c * 36 + ts] += coef * elu_f(accv[j]);
      }
      __syncthreads();
    }
  }

  // --- conv(k3,p1)+elu -> z (zzp) ---
  {
    int c = tid >> 2, q = tid & 3;                 // ts = q*9+j, guard <34
    const float* wp = W3z + c * 192;
    float accv[9];
    float bias = b3z[c];
#pragma unroll
    for(int j = 0; j < 9; ++j) accv[j] = bias;
    for(int i = 0; i < 64; ++i){
      float w0 = wp[i*3+0], w1 = wp[i*3+1], w2v = wp[i*3+2];
      const float* zp = &zinp[i * 36 + q * 9];
#pragma unroll
      for(int j = 0; j < 9; ++j)
        accv[j] += w0*zp[j] + w1*zp[j+1] + w2v*zp[j+2];
    }
    __syncthreads();
#pragma unroll
    for(int j = 0; j < 9; ++j){
      int ts = q * 9 + j;
      if(ts < 34){
        int t = t0 - 1 + ts;
        zzp[c * 34 + ts] = (t >= 0 && t < TM1) ? elu_f(accv[j]) : 0.f;
      }
    }
    __syncthreads();
  }

  // --- affs conv(k3,p1)+elu (output, transposed) ---
  if(tid < 128){
    int a = tid >> 5, tt = tid & 31;
    const float* wp = Wza + a * 192;
    float acc = bza[a];
    for(int i = 0; i < 64; ++i){
      const float* zp = &zzp[i * 34 + tt];
      acc += wp[i*3+0]*zp[0] + wp[i*3+1]*zp[1] + wp[i*3+2]*zp[2];
    }
    float av = elu_f(acc);
    affp[a * 32 + tt] = av;
    int t = t0 + tt;
    if(t < TM1) out_affs[((size_t)b * TM1 + t) * 4 + a] = av;
  }
  __syncthreads();

  // --- lbl1 = elu(W4 . affs + b4) -> lblA[128][32] (overwrites zin/zz) ---
  for(int idx = tid; idx < 4096; idx += 256){
    int d = idx >> 5, tt = idx & 31;
    float acc = b4[d] + W4[d*4+0]*affp[tt] + W4[d*4+1]*affp[32+tt]
              + W4[d*4+2]*affp[64+tt] + W4[d*4+3]*affp[96+tt];
    lblA[idx] = elu_f(acc);
  }
  __syncthreads();

  // --- lbl2 = elu(W5 . lbl1 + b5); BN over t; logits; sigmoid ---
  {
    int tt = tid >> 3, dg = tid & 7;               // d = dg*16+dd
    float l2[16];
#pragma unroll
    for(int dd = 0; dd < 16; ++dd) l2[dd] = b5[dg * 16 + dd];
    for(int cc = 0; cc < 128; ++cc){
      float xv = lblA[cc * 32 + tt];
#pragma unroll
      for(int dd = 0; dd < 16; ++dd)
        l2[dd] += W5[(dg * 16 + dd) * 128 + cc] * xv;
    }
    int t = t0 + tt;
    float sc = 0.f, bb = 0.f;
    if(t < TM1){ sc = gmm[t] * rsqrtf(1.f + 1e-5f); bb = bet[t]; }
    float lg[4] = {0.f, 0.f, 0.f, 0.f};
#pragma unroll
    for(int dd = 0; dd < 16; ++dd){
      int d = dg * 16 + dd;
      float val = elu_f(l2[dd]) * sc + bb;
#pragma unroll
      for(int c = 0; c < 4; ++c) lg[c] += Wc[c * 128 + d] * val;
    }
    __syncthreads();
#pragma unroll
    for(int c = 0; c < 4; ++c) lgpp[(tt * 8 + dg) * 4 + c] = lg[c];
  }
  __syncthreads();
  if(tid < 128){
    int tt = tid >> 2, c = tid & 3;
    float s = bc[c];
#pragma unroll
    for(int dg = 0; dg < 8; ++dg) s += lgpp[(tt * 8 + dg) * 4 + c];
    int ta = t0 + tt;
    if(ta < TM1) out_lab[((size_t)b * TM1 + ta) * 4 + c] = sigm_f(s);
  }
}

extern "C" void kernel_launch(void* const* d_in, const int* in_sizes, int n_in,
                              void* d_out, int out_size, void* d_ws, size_t ws_size,
                              hipStream_t stream){
  (void)in_sizes; (void)n_in; (void)out_size; (void)ws_size;
  const float* x_diffs = (const float*)d_in[1];
  const float* h_init  = (const float*)d_in[3];
  const float* Wih0 = (const float*)d_in[4];
  const float* Whh0 = (const float*)d_in[5];
  const float* bih0 = (const float*)d_in[6];
  const float* bhh0 = (const float*)d_in[7];
  const float* Wih1 = (const float*)d_in[8];
  const float* Whh1 = (const float*)d_in[9];
  const float* bih1 = (const float*)d_in[10];
  const float* bhh1 = (const float*)d_in[11];
  const float* W2  = (const float*)d_in[12];
  const float* b2  = (const float*)d_in[13];
  const float* W3  = (const float*)d_in[14];
  const float* b3  = (const float*)d_in[15];
  const float* W3z = (const float*)d_in[16];
  const float* b3z = (const float*)d_in[17];
  const float* Wza = (const float*)d_in[18];
  const float* bza = (const float*)d_in[19];
  const float* W4  = (const float*)d_in[20];
  const float* b4  = (const float*)d_in[21];
  const float* W5  = (const float*)d_in[22];
  const float* b5  = (const float*)d_in[23];
  const float* gmm = (const float*)d_in[24];
  const float* bet = (const float*)d_in[25];
  const float* Wc  = (const float*)d_in[26];
  const float* bc  = (const float*)d_in[27];
  float* out = (float*)d_out;

  // workspace layout (floats): total ~149 MB
  float* ws   = (float*)d_ws;
  float* x_ws = ws;                       // 32*63*2047      = 4,126,752
  float* y1   = x_ws + 4126752;           // 32*2047*336     = 22,009,344
  float* gxb  = y1 + 22009344;            // 32*256*1008     =  8,257,536
  float* y0c  = gxb + 8257536;            // 32*256*336      =  2,752,512
  float* hb   = y0c + 2752512;            // 4*32*336        =     43,008
  int*   flg  = (int*)(hb + 43008);       // 2 layers * 16 pairs * 8 WGs * FLG_STRIDE

  float* out_affs = out;
  float* out_lab  = out + (size_t)NB * TM1 * 4;
  float* hT0 = out + 2 * (size_t)NB * TM1 * 4;
  float* hT1 = hT0 + NB * HH;

  (void)hipMemsetAsync(flg, 0, 2 * 16 * GU * FLG_STRIDE * sizeof(int), stream);
  (void)hipMemcpyAsync(hb,               h_init,           NB * HH * sizeof(float), hipMemcpyDeviceToDevice, stream);
  (void)hipMemcpyAsync(hb + 2 * NB * HH, h_init + NB * HH, NB * HH * sizeof(float), hipMemcpyDeviceToDevice, stream);

  k_euler<<<dim3(NB * NV), 256, 0, stream>>>(x_diffs, x_ws);

  for(int c = 0; c < 8; ++c){
    int t0 = c * CH;
    int tn = (TM1 - t0 < CH) ? (TM1 - t0) : CH;
    int gtiles = (tn + 63) / 64;
    k_gx<63, 63, true><<<dim3(gtiles, 16, NB), 256, 0, stream>>>(
        x_ws, 0, 0, Wih0, bih0, gxb, CH, t0);
    k_scan<<<dim3(GU * 16), SCAN_T, 0, stream>>>(
        Whh0, bhh0, gxb, CH, hb, hb + NB * HH, y0c, CH, t0, hT0, flg, t0, tn);
    k_gx<336, 112, false><<<dim3(gtiles, 16, NB), 256, 0, stream>>>(
        y0c, CH, t0, Wih1, bih1, gxb, CH, t0);
    k_scan<<<dim3(GU * 16), SCAN_T, 0, stream>>>(
        Whh1, bhh1, gxb, CH, hb + 2 * NB * HH, hb + 3 * NB * HH, y1, TM1, 0, hT1,
        flg + 16 * GU * FLG_STRIDE, t0, tn);
  }

  k_head<<<dim3(64, NB), 256, 0, stream>>>(y1, W2, b2, W3, b3, W3z, b3z, Wza, bza,
                                           W4, b4, W5, b5, gmm, bet, Wc, bc,
                                           out_affs, out_lab);
}